// Round 1
// baseline (40397.693 us; speedup 1.0000x reference)
//
#include <hip/hip_runtime.h>
#include <stdint.h>

// Embedder: 3-layer shared-weight GRU (B=64,T=2048,H=128) + sigmoid proj.
// v2: ONE workgroup per batch-quarter (grid=4, 512 thr = 8 waves) time-multiplexes
// all four pipeline phases per tick:  L0(tau), L1(tau-1), L2(tau-2), Out(tau-3).
// Shared weights => one register-resident B-fragment set serves all 3 GRU layers.
// All inter-layer handoff via LDS double-buffered A-fragment buffers; the
// recurrent read of layer l IS the input read of layer l+1 (read once per tick).
// No cross-WG traffic, no flags, no agent atomics, no spin loops.
#define TSEQ 2048
#define HD   128
#define G3   384

typedef __bf16 bf16_t;
typedef __bf16 bf16x8 __attribute__((ext_vector_type(8)));
typedef float  f32x4  __attribute__((ext_vector_type(4)));

union B8 { uint4 u; bf16x8 v; unsigned a4[4]; };

__device__ __forceinline__ float fast_sigmoid(float x) {
    float e = __builtin_amdgcn_exp2f(-1.44269504f * x);
    return __builtin_amdgcn_rcpf(1.0f + e);
}
__device__ __forceinline__ float fast_tanh(float x) {
    x = fminf(9.0f, fmaxf(-9.0f, x));
    float e = __builtin_amdgcn_exp2f(2.88539008f * x);   // exp(2x)
    return 1.0f - 2.0f * __builtin_amdgcn_rcpf(1.0f + e);
}

#define MFMA16(A_, B_, C_) (C_) = __builtin_amdgcn_mfma_f32_16x16x32_bf16((A_), (B_), (C_), 0, 0, 0)

// MFMA 16x16x32 bf16 fragment maps (HW-verified layout, carried from v1):
//   A: lane l, elem j -> A[l&15][(l>>4)*8 + j]
//   B: lane l, elem j -> B[(l>>4)*8 + j][l&15]
//   C/D: lane l, reg i -> C[(l>>4)*4 + i][l&15]

// One GRU cell evaluation for phase writing interface IF at parity PP.
// (XH,XL) = upstream hi/lo A-frags; (AH,AL) = own-h hi/lo A-frags; HP = fp32 h state.
#define GRU_PHASE(XH, XL, AH, AL, HP, IF, PP)                               \
  { f32x4 accZ  = {bZ, bZ, bZ, bZ};                                         \
    f32x4 accR  = {bR, bR, bR, bR};                                         \
    f32x4 accXC = {bXC, bXC, bXC, bXC};                                     \
    f32x4 accHC = {bHC, bHC, bHC, bHC};                                     \
    _Pragma("unroll") for (int q = 0; q < 4; ++q) {                         \
      MFMA16(XH[q].v, Bi_[0][q], accZ);                                     \
      MFMA16(XH[q].v, Bi_[1][q], accR);                                     \
      MFMA16(XH[q].v, Bi_[2][q], accXC);                                    \
      MFMA16(XL[q].v, Bi_[0][q], accZ);                                     \
      MFMA16(XL[q].v, Bi_[1][q], accR);                                     \
      MFMA16(XL[q].v, Bi_[2][q], accXC);                                    \
    }                                                                       \
    _Pragma("unroll") for (int q = 0; q < 4; ++q) {                         \
      MFMA16(AH[q].v, Br_[0][q], accZ);                                     \
      MFMA16(AH[q].v, Br_[1][q], accR);                                     \
      MFMA16(AH[q].v, Br_[2][q], accHC);                                    \
      MFMA16(AL[q].v, Br_[0][q], accZ);                                     \
      MFMA16(AL[q].v, Br_[1][q], accR);                                     \
      MFMA16(AL[q].v, Br_[2][q], accHC);                                    \
    }                                                                       \
    _Pragma("unroll") for (int i = 0; i < 4; ++i) {                         \
      const float zg = fast_sigmoid(accZ[i]);                               \
      const float rg = fast_sigmoid(accR[i]);                               \
      const float cd = fast_tanh(accXC[i] + rg * accHC[i]);                 \
      const float hn = cd + zg * (HP[i] - cd);                              \
      HP[i] = hn;                                                           \
      const bf16_t hh = (bf16_t)hn;                                         \
      const bf16_t hl = (bf16_t)(hn - (float)hh);                           \
      const int mrow = 4 * quad + i;                                        \
      ((bf16_t*)&ldsh[IF][PP][0][qq][lamb + mrow])[jj] = hh;                \
      ((bf16_t*)&ldsh[IF][PP][1][qq][lamb + mrow])[jj] = hl;                \
    } }

// One tick. Reads all parity PP^1 buffers (written last tick), writes parity PP.
// X for step TT+1 is register-staged early (load) / written to LDS late (T14).
#define TICK(TT, PP)                                                          \
  {                                                                           \
    uint4 xstage;                                                             \
    const bool do_stage = ((TT) + 1 < TSEQ);                                  \
    if (do_stage) xstage = *(const uint4*)(xsrc0 + (size_t)((TT) + 1) * HD);  \
    B8 xhi[4], xlo[4];                                                        \
    if ((TT) < TSEQ) {                                                        \
      const char* xb = (const char*)&ldsx[PP][0];                             \
      _Pragma("unroll") for (int q = 0; q < 4; ++q) {                         \
        const int base = l15 * 512 + (32 * q + 8 * quad) * 4;                 \
        const int sw   = (l15 & 7) << 4;                                      \
        const f32x4 f0 = *(const f32x4*)(xb + (base ^ sw));                   \
        const f32x4 f1 = *(const f32x4*)(xb + ((base + 16) ^ sw));            \
        _Pragma("unroll") for (int j = 0; j < 4; ++j) {                       \
          const bf16_t h0 = (bf16_t)f0[j];                                    \
          xhi[q].v[j] = h0;                                                   \
          xlo[q].v[j] = (bf16_t)(f0[j] - (float)h0);                          \
          const bf16_t h1 = (bf16_t)f1[j];                                    \
          xhi[q].v[j + 4] = h1;                                               \
          xlo[q].v[j + 4] = (bf16_t)(f1[j] - (float)h1);                      \
        }                                                                     \
      }                                                                       \
    }                                                                         \
    B8 a0h[4], a0l[4], a1h[4], a1l[4], a2h[4], a2l[4];                        \
    if ((TT) <= TSEQ)                                                         \
      _Pragma("unroll") for (int q = 0; q < 4; ++q) {                         \
        a0h[q].u = ldsh[0][(PP) ^ 1][0][q][lane];                             \
        a0l[q].u = ldsh[0][(PP) ^ 1][1][q][lane];                             \
      }                                                                       \
    if ((TT) < TSEQ) GRU_PHASE(xhi, xlo, a0h, a0l, hp0, 0, PP)                \
    if ((TT) >= 1 && (TT) <= TSEQ + 1)                                        \
      _Pragma("unroll") for (int q = 0; q < 4; ++q) {                         \
        a1h[q].u = ldsh[1][(PP) ^ 1][0][q][lane];                             \
        a1l[q].u = ldsh[1][(PP) ^ 1][1][q][lane];                             \
      }                                                                       \
    if ((TT) >= 1 && (TT) < TSEQ + 1) GRU_PHASE(a0h, a0l, a1h, a1l, hp1, 1, PP) \
    if ((TT) >= 2)                                                            \
      _Pragma("unroll") for (int q = 0; q < 4; ++q) {                         \
        a2h[q].u = ldsh[2][(PP) ^ 1][0][q][lane];                             \
        a2l[q].u = ldsh[2][(PP) ^ 1][1][q][lane];                             \
      }                                                                       \
    if ((TT) >= 2 && (TT) < TSEQ + 2) GRU_PHASE(a1h, a1l, a2h, a2l, hp2, 2, PP) \
    if ((TT) >= 3 && (TT) < TSEQ + 3) {                                       \
      f32x4 acc = {bb, bb, bb, bb};                                           \
      _Pragma("unroll") for (int q = 0; q < 4; ++q) {                         \
        MFMA16(a2h[q].v, Bw[q], acc);                                         \
        MFMA16(a2l[q].v, Bw[q], acc);                                         \
      }                                                                       \
      const int t3 = (TT) - 3;                                                \
      _Pragma("unroll") for (int i = 0; i < 4; ++i)                           \
        out[((size_t)(16 * b + 4 * quad + i) * TSEQ + t3) * HD + cc] =        \
            fast_sigmoid(acc[i]);                                             \
    }                                                                         \
    if (do_stage) *(uint4*)((char*)&ldsx[(PP) ^ 1][0] + tid * 16) = xstage;   \
    __syncthreads();                                                          \
  }

__global__ __launch_bounds__(512, 2) void fused_gru(
    const float* __restrict__ X,
    const float* __restrict__ Wk, const float* __restrict__ Wr,
    const float* __restrict__ bi, const float* __restrict__ br,
    const float* __restrict__ Wo, const float* __restrict__ bo,
    float* __restrict__ out)
{
    // h exchange buffers: [iface(L0,L1,L2 out)][parity][hi/lo][q][lane], A-frag packed.
    __shared__ uint4 ldsh[3][2][2][4][64];   // 48 KB
    // X tile, fp32, XOR-swizzled (source-swizzled write, XOR read => <=2-way conflicts)
    __shared__ float ldsx[2][16 * HD];       // 16 KB

    const int b    = blockIdx.x;             // batch quarter (16 rows)
    const int tid  = threadIdx.x;
    const int w    = tid >> 6;
    const int lane = tid & 63;
    const int l15  = lane & 15;
    const int quad = lane >> 4;

    // Resident B-fragments. Weights are SHARED across all 3 GRU layers, so one
    // copy (96 VGPRs) serves every phase. Wave w owns gate-cols [16w,16w+16).
    bf16x8 Br_[3][4], Bi_[3][4], Bw[4];
#pragma unroll
    for (int g = 0; g < 3; ++g)
#pragma unroll
        for (int q = 0; q < 4; ++q) {
            const int col = 128 * g + 16 * w + l15;
#pragma unroll
            for (int j = 0; j < 8; ++j) {
                const int row = 32 * q + 8 * quad + j;
                Br_[g][q][j] = (bf16_t)Wr[row * G3 + col];
                Bi_[g][q][j] = (bf16_t)Wk[row * G3 + col];
            }
        }
#pragma unroll
    for (int q = 0; q < 4; ++q)
#pragma unroll
        for (int j = 0; j < 8; ++j)
            Bw[q][j] = (bf16_t)Wo[(32 * q + 8 * quad + j) * HD + 16 * w + l15];

    const int   cc  = 16 * w + l15;
    const float bZ  = bi[cc] + br[cc];
    const float bR  = bi[128 + cc] + br[128 + cc];
    const float bXC = bi[256 + cc];
    const float bHC = br[256 + cc];
    const float bb  = bo[cc];

    // LDS h-write mapping: A[mrow][cc] -> frag q=cc>>5, lane=mrow+16*((cc>>3)&3), elem cc&7
    const int qq   = cc >> 5;
    const int lamb = 16 * ((cc >> 3) & 3);
    const int jj   = cc & 7;

    // zero all h buffers: h(-1) = 0 for every layer, both parities
    {
        uint4 z4; z4.x = z4.y = z4.z = z4.w = 0u;
        for (int i = tid; i < 3 * 2 * 2 * 4 * 64; i += 512) ((uint4*)ldsh)[i] = z4;
    }

    // X staging geometry: thread tid -> row=tid>>5, linear LDS dest tid*16; the
    // SOURCE 16B-group is XOR-swizzled so the read-side XOR lands conflict-free.
    const int xrow = tid >> 5;
    const int xcg  = (tid & 31) ^ (xrow & 7);
    const float* xsrc0 = X + (size_t)(16 * b + xrow) * TSEQ * HD + 4 * xcg;

    {   // prologue: stage X(t=0) into parity 0
        const uint4 x0 = *(const uint4*)xsrc0;
        *(uint4*)((char*)&ldsx[0][0] + tid * 16) = x0;
    }
    __syncthreads();

    float hp0[4] = {0.f, 0.f, 0.f, 0.f};
    float hp1[4] = {0.f, 0.f, 0.f, 0.f};
    float hp2[4] = {0.f, 0.f, 0.f, 0.f};

    // 2051 real ticks (+1 dead pad tick so the 2x parity unroll stays literal)
    for (int tau = 0; tau < TSEQ + 4; tau += 2) {
        TICK(tau, 0)
        TICK(tau + 1, 1)
    }
}

extern "C" void kernel_launch(void* const* d_in, const int* in_sizes, int n_in,
                              void* d_out, int out_size, void* d_ws, size_t ws_size,
                              hipStream_t stream) {
    const float* X  = (const float*)d_in[0];
    const float* Wk = (const float*)d_in[1];
    const float* Wr = (const float*)d_in[2];
    const float* bi = (const float*)d_in[3];
    const float* br = (const float*)d_in[4];
    const float* Wo = (const float*)d_in[5];
    const float* bo = (const float*)d_in[6];
    float* out = (float*)d_out;
    (void)d_ws; (void)ws_size;  // no workspace needed: no rings, no flags

    fused_gru<<<4, 512, 0, stream>>>(X, Wk, Wr, bi, br, Wo, bo, out);
}

// Round 2
// 40205.505 us; speedup vs baseline: 1.0048x; 1.0048x over previous
//
#include <hip/hip_runtime.h>
#include <stdint.h>

// Embedder: 3-layer shared-weight GRU (B=64,T=2048,H=128) + sigmoid proj.
// v3: same single-WG-per-quarter time-multiplexed pipeline as v2, with the
// register-spill bug fixed: __launch_bounds__(512,1) gives 256 VGPR/wave
// (v2's (512,2) capped at 128 and spilled ~100 regs/lane -> scratch treadmill).
// Grid is 4 WGs so >1 block/CU is useless anyway.
// Also: lgkmcnt-only tick barrier (out-stores / X-prefetch stay in flight).
#define TSEQ 2048
#define HD   128
#define G3   384

typedef __bf16 bf16_t;
typedef __bf16 bf16x8 __attribute__((ext_vector_type(8)));
typedef float  f32x4  __attribute__((ext_vector_type(4)));

union B8 { uint4 u; bf16x8 v; unsigned a4[4]; };

__device__ __forceinline__ float fast_sigmoid(float x) {
    float e = __builtin_amdgcn_exp2f(-1.44269504f * x);
    return __builtin_amdgcn_rcpf(1.0f + e);
}
__device__ __forceinline__ float fast_tanh(float x) {
    x = fminf(9.0f, fmaxf(-9.0f, x));
    float e = __builtin_amdgcn_exp2f(2.88539008f * x);   // exp(2x)
    return 1.0f - 2.0f * __builtin_amdgcn_rcpf(1.0f + e);
}

#define MFMA16(A_, B_, C_) (C_) = __builtin_amdgcn_mfma_f32_16x16x32_bf16((A_), (B_), (C_), 0, 0, 0)

// Tick barrier: LDS visibility only. The only cross-wave dependency per tick is
// ldsh/ldsx (LDS); global out-stores and the X prefetch may stay in flight.
__device__ __forceinline__ void fast_barrier() {
    asm volatile("s_waitcnt lgkmcnt(0)\n\ts_barrier" ::: "memory");
}

// MFMA 16x16x32 bf16 fragment maps (HW-verified layout, carried from v1):
//   A: lane l, elem j -> A[l&15][(l>>4)*8 + j]
//   B: lane l, elem j -> B[(l>>4)*8 + j][l&15]
//   C/D: lane l, reg i -> C[(l>>4)*4 + i][l&15]

// One GRU cell evaluation for phase writing interface IF at parity PP.
// (XH,XL) = upstream hi/lo A-frags; (AH,AL) = own-h hi/lo A-frags; HP = fp32 h state.
#define GRU_PHASE(XH, XL, AH, AL, HP, IF, PP)                               \
  { f32x4 accZ  = {bZ, bZ, bZ, bZ};                                         \
    f32x4 accR  = {bR, bR, bR, bR};                                         \
    f32x4 accXC = {bXC, bXC, bXC, bXC};                                     \
    f32x4 accHC = {bHC, bHC, bHC, bHC};                                     \
    _Pragma("unroll") for (int q = 0; q < 4; ++q) {                         \
      MFMA16(XH[q].v, Bi_[0][q], accZ);                                     \
      MFMA16(XH[q].v, Bi_[1][q], accR);                                     \
      MFMA16(XH[q].v, Bi_[2][q], accXC);                                    \
      MFMA16(XL[q].v, Bi_[0][q], accZ);                                     \
      MFMA16(XL[q].v, Bi_[1][q], accR);                                     \
      MFMA16(XL[q].v, Bi_[2][q], accXC);                                    \
    }                                                                       \
    _Pragma("unroll") for (int q = 0; q < 4; ++q) {                         \
      MFMA16(AH[q].v, Br_[0][q], accZ);                                     \
      MFMA16(AH[q].v, Br_[1][q], accR);                                     \
      MFMA16(AH[q].v, Br_[2][q], accHC);                                    \
      MFMA16(AL[q].v, Br_[0][q], accZ);                                     \
      MFMA16(AL[q].v, Br_[1][q], accR);                                     \
      MFMA16(AL[q].v, Br_[2][q], accHC);                                    \
    }                                                                       \
    _Pragma("unroll") for (int i = 0; i < 4; ++i) {                         \
      const float zg = fast_sigmoid(accZ[i]);                               \
      const float rg = fast_sigmoid(accR[i]);                               \
      const float cd = fast_tanh(accXC[i] + rg * accHC[i]);                 \
      const float hn = cd + zg * (HP[i] - cd);                              \
      HP[i] = hn;                                                           \
      const bf16_t hh = (bf16_t)hn;                                         \
      const bf16_t hl = (bf16_t)(hn - (float)hh);                           \
      const int mrow = 4 * quad + i;                                        \
      ((bf16_t*)&ldsh[IF][PP][0][qq][lamb + mrow])[jj] = hh;                \
      ((bf16_t*)&ldsh[IF][PP][1][qq][lamb + mrow])[jj] = hl;                \
    } }

// One tick. Reads all parity PP^1 buffers (written last tick), writes parity PP.
// X for step TT+1 is register-staged early (load) / written to LDS late (T14).
#define TICK(TT, PP)                                                          \
  {                                                                           \
    uint4 xstage;                                                             \
    const bool do_stage = ((TT) + 1 < TSEQ);                                  \
    if (do_stage) xstage = *(const uint4*)(xsrc0 + (size_t)((TT) + 1) * HD);  \
    B8 xhi[4], xlo[4];                                                        \
    if ((TT) < TSEQ) {                                                        \
      const char* xb = (const char*)&ldsx[PP][0];                             \
      _Pragma("unroll") for (int q = 0; q < 4; ++q) {                         \
        const int base = l15 * 512 + (32 * q + 8 * quad) * 4;                 \
        const int sw   = (l15 & 7) << 4;                                      \
        const f32x4 f0 = *(const f32x4*)(xb + (base ^ sw));                   \
        const f32x4 f1 = *(const f32x4*)(xb + ((base + 16) ^ sw));            \
        _Pragma("unroll") for (int j = 0; j < 4; ++j) {                       \
          const bf16_t h0 = (bf16_t)f0[j];                                    \
          xhi[q].v[j] = h0;                                                   \
          xlo[q].v[j] = (bf16_t)(f0[j] - (float)h0);                          \
          const bf16_t h1 = (bf16_t)f1[j];                                    \
          xhi[q].v[j + 4] = h1;                                               \
          xlo[q].v[j + 4] = (bf16_t)(f1[j] - (float)h1);                      \
        }                                                                     \
      }                                                                       \
    }                                                                         \
    B8 a0h[4], a0l[4], a1h[4], a1l[4], a2h[4], a2l[4];                        \
    if ((TT) <= TSEQ)                                                         \
      _Pragma("unroll") for (int q = 0; q < 4; ++q) {                         \
        a0h[q].u = ldsh[0][(PP) ^ 1][0][q][lane];                             \
        a0l[q].u = ldsh[0][(PP) ^ 1][1][q][lane];                             \
      }                                                                       \
    if ((TT) < TSEQ) GRU_PHASE(xhi, xlo, a0h, a0l, hp0, 0, PP)                \
    if ((TT) >= 1 && (TT) <= TSEQ + 1)                                        \
      _Pragma("unroll") for (int q = 0; q < 4; ++q) {                         \
        a1h[q].u = ldsh[1][(PP) ^ 1][0][q][lane];                             \
        a1l[q].u = ldsh[1][(PP) ^ 1][1][q][lane];                             \
      }                                                                       \
    if ((TT) >= 1 && (TT) < TSEQ + 1) GRU_PHASE(a0h, a0l, a1h, a1l, hp1, 1, PP) \
    if ((TT) >= 2)                                                            \
      _Pragma("unroll") for (int q = 0; q < 4; ++q) {                         \
        a2h[q].u = ldsh[2][(PP) ^ 1][0][q][lane];                             \
        a2l[q].u = ldsh[2][(PP) ^ 1][1][q][lane];                             \
      }                                                                       \
    if ((TT) >= 2 && (TT) < TSEQ + 2) GRU_PHASE(a1h, a1l, a2h, a2l, hp2, 2, PP) \
    if ((TT) >= 3 && (TT) < TSEQ + 3) {                                       \
      f32x4 acc = {bb, bb, bb, bb};                                           \
      _Pragma("unroll") for (int q = 0; q < 4; ++q) {                         \
        MFMA16(a2h[q].v, Bw[q], acc);                                         \
        MFMA16(a2l[q].v, Bw[q], acc);                                         \
      }                                                                       \
      const int t3 = (TT) - 3;                                                \
      _Pragma("unroll") for (int i = 0; i < 4; ++i)                           \
        out[((size_t)(16 * b + 4 * quad + i) * TSEQ + t3) * HD + cc] =        \
            fast_sigmoid(acc[i]);                                             \
    }                                                                         \
    if (do_stage) *(uint4*)((char*)&ldsx[(PP) ^ 1][0] + tid * 16) = xstage;   \
    fast_barrier();                                                           \
  }

__global__ __launch_bounds__(512, 1) void fused_gru(
    const float* __restrict__ X,
    const float* __restrict__ Wk, const float* __restrict__ Wr,
    const float* __restrict__ bi, const float* __restrict__ br,
    const float* __restrict__ Wo, const float* __restrict__ bo,
    float* __restrict__ out)
{
    // h exchange buffers: [iface(L0,L1,L2 out)][parity][hi/lo][q][lane], A-frag packed.
    __shared__ uint4 ldsh[3][2][2][4][64];   // 48 KB
    // X tile, fp32, XOR-swizzled (source-swizzled write, XOR read => <=2-way conflicts)
    __shared__ float ldsx[2][16 * HD];       // 16 KB

    const int b    = blockIdx.x;             // batch quarter (16 rows)
    const int tid  = threadIdx.x;
    const int w    = tid >> 6;
    const int lane = tid & 63;
    const int l15  = lane & 15;
    const int quad = lane >> 4;

    // Resident B-fragments. Weights are SHARED across all 3 GRU layers, so one
    // copy (112 VGPRs) serves every phase. Wave w owns gate-cols [16w,16w+16).
    bf16x8 Br_[3][4], Bi_[3][4], Bw[4];
#pragma unroll
    for (int g = 0; g < 3; ++g)
#pragma unroll
        for (int q = 0; q < 4; ++q) {
            const int col = 128 * g + 16 * w + l15;
#pragma unroll
            for (int j = 0; j < 8; ++j) {
                const int row = 32 * q + 8 * quad + j;
                Br_[g][q][j] = (bf16_t)Wr[row * G3 + col];
                Bi_[g][q][j] = (bf16_t)Wk[row * G3 + col];
            }
        }
#pragma unroll
    for (int q = 0; q < 4; ++q)
#pragma unroll
        for (int j = 0; j < 8; ++j)
            Bw[q][j] = (bf16_t)Wo[(32 * q + 8 * quad + j) * HD + 16 * w + l15];

    const int   cc  = 16 * w + l15;
    const float bZ  = bi[cc] + br[cc];
    const float bR  = bi[128 + cc] + br[128 + cc];
    const float bXC = bi[256 + cc];
    const float bHC = br[256 + cc];
    const float bb  = bo[cc];

    // LDS h-write mapping: A[mrow][cc] -> frag q=cc>>5, lane=mrow+16*((cc>>3)&3), elem cc&7
    const int qq   = cc >> 5;
    const int lamb = 16 * ((cc >> 3) & 3);
    const int jj   = cc & 7;

    // zero all h buffers: h(-1) = 0 for every layer, both parities
    {
        uint4 z4; z4.x = z4.y = z4.z = z4.w = 0u;
        for (int i = tid; i < 3 * 2 * 2 * 4 * 64; i += 512) ((uint4*)ldsh)[i] = z4;
    }

    // X staging geometry: thread tid -> row=tid>>5, linear LDS dest tid*16; the
    // SOURCE 16B-group is XOR-swizzled so the read-side XOR lands conflict-free.
    const int xrow = tid >> 5;
    const int xcg  = (tid & 31) ^ (xrow & 7);
    const float* xsrc0 = X + (size_t)(16 * b + xrow) * TSEQ * HD + 4 * xcg;

    {   // prologue: stage X(t=0) into parity 0
        const uint4 x0 = *(const uint4*)xsrc0;
        *(uint4*)((char*)&ldsx[0][0] + tid * 16) = x0;
    }
    __syncthreads();

    float hp0[4] = {0.f, 0.f, 0.f, 0.f};
    float hp1[4] = {0.f, 0.f, 0.f, 0.f};
    float hp2[4] = {0.f, 0.f, 0.f, 0.f};

    // 2051 real ticks (+1 dead pad tick so the 2x parity unroll stays literal)
    for (int tau = 0; tau < TSEQ + 4; tau += 2) {
        TICK(tau, 0)
        TICK(tau + 1, 1)
    }
}

extern "C" void kernel_launch(void* const* d_in, const int* in_sizes, int n_in,
                              void* d_out, int out_size, void* d_ws, size_t ws_size,
                              hipStream_t stream) {
    const float* X  = (const float*)d_in[0];
    const float* Wk = (const float*)d_in[1];
    const float* Wr = (const float*)d_in[2];
    const float* bi = (const float*)d_in[3];
    const float* br = (const float*)d_in[4];
    const float* Wo = (const float*)d_in[5];
    const float* bo = (const float*)d_in[6];
    float* out = (float*)d_out;
    (void)d_ws; (void)ws_size;  // no workspace needed: no rings, no flags

    fused_gru<<<4, 512, 0, stream>>>(X, Wk, Wr, bi, br, Wo, bo, out);
}

// Round 3
// 40196.466 us; speedup vs baseline: 1.0050x; 1.0002x over previous
//
#include <hip/hip_runtime.h>
#include <stdint.h>

// Embedder: 3-layer shared-weight GRU (B=64,T=2048,H=128) + sigmoid proj.
// v4: same time-multiplexed single-WG pipeline as v2/v3. Fix: the register
// allocator was targeting 4 waves/EU (LDS=64KB allows 2 blocks/CU) and capped
// VGPRs at 128, spilling ~100 regs/lane -> scratch treadmill (39k cyc/tick).
// Grid is 4 WGs so a 2nd resident block never exists. amdgpu_waves_per_eu(2,2)
// states the truth (8 waves, 1 block/CU) -> 256-VGPR budget -> no spills.
#define TSEQ 2048
#define HD   128
#define G3   384

typedef __bf16 bf16_t;
typedef __bf16 bf16x8 __attribute__((ext_vector_type(8)));
typedef float  f32x4  __attribute__((ext_vector_type(4)));

union B8 { uint4 u; bf16x8 v; unsigned a4[4]; };

__device__ __forceinline__ float fast_sigmoid(float x) {
    float e = __builtin_amdgcn_exp2f(-1.44269504f * x);
    return __builtin_amdgcn_rcpf(1.0f + e);
}
__device__ __forceinline__ float fast_tanh(float x) {
    x = fminf(9.0f, fmaxf(-9.0f, x));
    float e = __builtin_amdgcn_exp2f(2.88539008f * x);   // exp(2x)
    return 1.0f - 2.0f * __builtin_amdgcn_rcpf(1.0f + e);
}

#define MFMA16(A_, B_, C_) (C_) = __builtin_amdgcn_mfma_f32_16x16x32_bf16((A_), (B_), (C_), 0, 0, 0)

// Tick barrier: LDS visibility only. The only cross-wave dependency per tick is
// ldsh/ldsx (LDS); global out-stores and the X prefetch may stay in flight.
__device__ __forceinline__ void fast_barrier() {
    asm volatile("s_waitcnt lgkmcnt(0)\n\ts_barrier" ::: "memory");
}

// MFMA 16x16x32 bf16 fragment maps (HW-verified layout, carried from v1):
//   A: lane l, elem j -> A[l&15][(l>>4)*8 + j]
//   B: lane l, elem j -> B[(l>>4)*8 + j][l&15]
//   C/D: lane l, reg i -> C[(l>>4)*4 + i][l&15]

// One GRU cell evaluation for phase writing interface IF at parity PP.
// (XH,XL) = upstream hi/lo A-frags; (AH,AL) = own-h hi/lo A-frags; HP = fp32 h state.
#define GRU_PHASE(XH, XL, AH, AL, HP, IF, PP)                               \
  { f32x4 accZ  = {bZ, bZ, bZ, bZ};                                         \
    f32x4 accR  = {bR, bR, bR, bR};                                         \
    f32x4 accXC = {bXC, bXC, bXC, bXC};                                     \
    f32x4 accHC = {bHC, bHC, bHC, bHC};                                     \
    _Pragma("unroll") for (int q = 0; q < 4; ++q) {                         \
      MFMA16(XH[q].v, Bi_[0][q], accZ);                                     \
      MFMA16(XH[q].v, Bi_[1][q], accR);                                     \
      MFMA16(XH[q].v, Bi_[2][q], accXC);                                    \
      MFMA16(XL[q].v, Bi_[0][q], accZ);                                     \
      MFMA16(XL[q].v, Bi_[1][q], accR);                                     \
      MFMA16(XL[q].v, Bi_[2][q], accXC);                                    \
    }                                                                       \
    _Pragma("unroll") for (int q = 0; q < 4; ++q) {                         \
      MFMA16(AH[q].v, Br_[0][q], accZ);                                     \
      MFMA16(AH[q].v, Br_[1][q], accR);                                     \
      MFMA16(AH[q].v, Br_[2][q], accHC);                                    \
      MFMA16(AL[q].v, Br_[0][q], accZ);                                     \
      MFMA16(AL[q].v, Br_[1][q], accR);                                     \
      MFMA16(AL[q].v, Br_[2][q], accHC);                                    \
    }                                                                       \
    _Pragma("unroll") for (int i = 0; i < 4; ++i) {                         \
      const float zg = fast_sigmoid(accZ[i]);                               \
      const float rg = fast_sigmoid(accR[i]);                               \
      const float cd = fast_tanh(accXC[i] + rg * accHC[i]);                 \
      const float hn = cd + zg * (HP[i] - cd);                              \
      HP[i] = hn;                                                           \
      const bf16_t hh = (bf16_t)hn;                                         \
      const bf16_t hl = (bf16_t)(hn - (float)hh);                           \
      const int mrow = 4 * quad + i;                                        \
      ((bf16_t*)&ldsh[IF][PP][0][qq][lamb + mrow])[jj] = hh;                \
      ((bf16_t*)&ldsh[IF][PP][1][qq][lamb + mrow])[jj] = hl;                \
    } }

// One tick. Reads all parity PP^1 buffers (written last tick), writes parity PP.
// X for step TT+1 is register-staged early (load) / written to LDS late (T14).
#define TICK(TT, PP)                                                          \
  {                                                                           \
    uint4 xstage;                                                             \
    const bool do_stage = ((TT) + 1 < TSEQ);                                  \
    if (do_stage) xstage = *(const uint4*)(xsrc0 + (size_t)((TT) + 1) * HD);  \
    B8 xhi[4], xlo[4];                                                        \
    if ((TT) < TSEQ) {                                                        \
      const char* xb = (const char*)&ldsx[PP][0];                             \
      _Pragma("unroll") for (int q = 0; q < 4; ++q) {                         \
        const int base = l15 * 512 + (32 * q + 8 * quad) * 4;                 \
        const int sw   = (l15 & 7) << 4;                                      \
        const f32x4 f0 = *(const f32x4*)(xb + (base ^ sw));                   \
        const f32x4 f1 = *(const f32x4*)(xb + ((base + 16) ^ sw));            \
        _Pragma("unroll") for (int j = 0; j < 4; ++j) {                       \
          const bf16_t h0 = (bf16_t)f0[j];                                    \
          xhi[q].v[j] = h0;                                                   \
          xlo[q].v[j] = (bf16_t)(f0[j] - (float)h0);                          \
          const bf16_t h1 = (bf16_t)f1[j];                                    \
          xhi[q].v[j + 4] = h1;                                               \
          xlo[q].v[j + 4] = (bf16_t)(f1[j] - (float)h1);                      \
        }                                                                     \
      }                                                                       \
    }                                                                         \
    B8 a0h[4], a0l[4], a1h[4], a1l[4], a2h[4], a2l[4];                        \
    if ((TT) <= TSEQ)                                                         \
      _Pragma("unroll") for (int q = 0; q < 4; ++q) {                         \
        a0h[q].u = ldsh[0][(PP) ^ 1][0][q][lane];                             \
        a0l[q].u = ldsh[0][(PP) ^ 1][1][q][lane];                             \
      }                                                                       \
    if ((TT) < TSEQ) GRU_PHASE(xhi, xlo, a0h, a0l, hp0, 0, PP)                \
    if ((TT) >= 1 && (TT) <= TSEQ + 1)                                        \
      _Pragma("unroll") for (int q = 0; q < 4; ++q) {                         \
        a1h[q].u = ldsh[1][(PP) ^ 1][0][q][lane];                             \
        a1l[q].u = ldsh[1][(PP) ^ 1][1][q][lane];                             \
      }                                                                       \
    if ((TT) >= 1 && (TT) < TSEQ + 1) GRU_PHASE(a0h, a0l, a1h, a1l, hp1, 1, PP) \
    if ((TT) >= 2)                                                            \
      _Pragma("unroll") for (int q = 0; q < 4; ++q) {                         \
        a2h[q].u = ldsh[2][(PP) ^ 1][0][q][lane];                             \
        a2l[q].u = ldsh[2][(PP) ^ 1][1][q][lane];                             \
      }                                                                       \
    if ((TT) >= 2 && (TT) < TSEQ + 2) GRU_PHASE(a1h, a1l, a2h, a2l, hp2, 2, PP) \
    if ((TT) >= 3 && (TT) < TSEQ + 3) {                                       \
      f32x4 acc = {bb, bb, bb, bb};                                           \
      _Pragma("unroll") for (int q = 0; q < 4; ++q) {                         \
        MFMA16(a2h[q].v, Bw[q], acc);                                         \
        MFMA16(a2l[q].v, Bw[q], acc);                                         \
      }                                                                       \
      const int t3 = (TT) - 3;                                                \
      _Pragma("unroll") for (int i = 0; i < 4; ++i)                           \
        out[((size_t)(16 * b + 4 * quad + i) * TSEQ + t3) * HD + cc] =        \
            fast_sigmoid(acc[i]);                                             \
    }                                                                         \
    if (do_stage) *(uint4*)((char*)&ldsx[(PP) ^ 1][0] + tid * 16) = xstage;   \
    fast_barrier();                                                           \
  }

// Exactly 512 threads, exactly 2 waves/EU (1 block/CU, grid=4): tells the
// register allocator the real occupancy so it budgets 256 VGPRs, not 128.
__global__ __attribute__((amdgpu_flat_work_group_size(512, 512),
                          amdgpu_waves_per_eu(2, 2))) void fused_gru(
    const float* __restrict__ X,
    const float* __restrict__ Wk, const float* __restrict__ Wr,
    const float* __restrict__ bi, const float* __restrict__ br,
    const float* __restrict__ Wo, const float* __restrict__ bo,
    float* __restrict__ out)
{
    // h exchange buffers: [iface(L0,L1,L2 out)][parity][hi/lo][q][lane], A-frag packed.
    __shared__ uint4 ldsh[3][2][2][4][64];   // 48 KB
    // X tile, fp32, XOR-swizzled (source-swizzled write, XOR read => <=2-way conflicts)
    __shared__ float ldsx[2][16 * HD];       // 16 KB

    const int b    = blockIdx.x;             // batch quarter (16 rows)
    const int tid  = threadIdx.x;
    const int w    = tid >> 6;
    const int lane = tid & 63;
    const int l15  = lane & 15;
    const int quad = lane >> 4;

    // Resident B-fragments. Weights are SHARED across all 3 GRU layers, so one
    // copy (112 VGPRs) serves every phase. Wave w owns gate-cols [16w,16w+16).
    bf16x8 Br_[3][4], Bi_[3][4], Bw[4];
#pragma unroll
    for (int g = 0; g < 3; ++g)
#pragma unroll
        for (int q = 0; q < 4; ++q) {
            const int col = 128 * g + 16 * w + l15;
#pragma unroll
            for (int j = 0; j < 8; ++j) {
                const int row = 32 * q + 8 * quad + j;
                Br_[g][q][j] = (bf16_t)Wr[row * G3 + col];
                Bi_[g][q][j] = (bf16_t)Wk[row * G3 + col];
            }
        }
#pragma unroll
    for (int q = 0; q < 4; ++q)
#pragma unroll
        for (int j = 0; j < 8; ++j)
            Bw[q][j] = (bf16_t)Wo[(32 * q + 8 * quad + j) * HD + 16 * w + l15];

    const int   cc  = 16 * w + l15;
    const float bZ  = bi[cc] + br[cc];
    const float bR  = bi[128 + cc] + br[128 + cc];
    const float bXC = bi[256 + cc];
    const float bHC = br[256 + cc];
    const float bb  = bo[cc];

    // LDS h-write mapping: A[mrow][cc] -> frag q=cc>>5, lane=mrow+16*((cc>>3)&3), elem cc&7
    const int qq   = cc >> 5;
    const int lamb = 16 * ((cc >> 3) & 3);
    const int jj   = cc & 7;

    // zero all h buffers: h(-1) = 0 for every layer, both parities
    {
        uint4 z4; z4.x = z4.y = z4.z = z4.w = 0u;
        for (int i = tid; i < 3 * 2 * 2 * 4 * 64; i += 512) ((uint4*)ldsh)[i] = z4;
    }

    // X staging geometry: thread tid -> row=tid>>5, linear LDS dest tid*16; the
    // SOURCE 16B-group is XOR-swizzled so the read-side XOR lands conflict-free.
    const int xrow = tid >> 5;
    const int xcg  = (tid & 31) ^ (xrow & 7);
    const float* xsrc0 = X + (size_t)(16 * b + xrow) * TSEQ * HD + 4 * xcg;

    {   // prologue: stage X(t=0) into parity 0
        const uint4 x0 = *(const uint4*)xsrc0;
        *(uint4*)((char*)&ldsx[0][0] + tid * 16) = x0;
    }
    __syncthreads();

    float hp0[4] = {0.f, 0.f, 0.f, 0.f};
    float hp1[4] = {0.f, 0.f, 0.f, 0.f};
    float hp2[4] = {0.f, 0.f, 0.f, 0.f};

    // 2051 real ticks (+1 dead pad tick so the 2x parity unroll stays literal)
    for (int tau = 0; tau < TSEQ + 4; tau += 2) {
        TICK(tau, 0)
        TICK(tau + 1, 1)
    }
}

extern "C" void kernel_launch(void* const* d_in, const int* in_sizes, int n_in,
                              void* d_out, int out_size, void* d_ws, size_t ws_size,
                              hipStream_t stream) {
    const float* X  = (const float*)d_in[0];
    const float* Wk = (const float*)d_in[1];
    const float* Wr = (const float*)d_in[2];
    const float* bi = (const float*)d_in[3];
    const float* br = (const float*)d_in[4];
    const float* Wo = (const float*)d_in[5];
    const float* bo = (const float*)d_in[6];
    float* out = (float*)d_out;
    (void)d_ws; (void)ws_size;  // no workspace needed: no rings, no flags

    fused_gru<<<4, 512, 0, stream>>>(X, Wk, Wr, bi, br, Wo, bo, out);
}